// Round 13
// baseline (345.484 us; speedup 1.0000x reference)
//
#include <hip/hip_runtime.h>

#define N_NODES 100000
#define N_EDGES 1600000
#define ET (N_EDGES + N_NODES)
#define NEG_SLOPE 0.2f

// bucket sort params
#define BSHIFT 9
#define BW 512                                  // nodes per bucket
#define NBUCK ((N_NODES + BW - 1) / BW)         // 196
#define BCAP 10240
#define BINCH 2048                              // edges per bin block

typedef unsigned short u16;
typedef unsigned int u32;

__device__ __forceinline__ float bf2f(u16 v) {
    return __uint_as_float(((u32)v) << 16);
}
__device__ __forceinline__ u16 f2bf(float f) {
    u32 u = __float_as_uint(f);
    u32 r = (u + 0x7FFFu + ((u >> 16) & 1u)) >> 16;  // RNE
    return (u16)r;
}
__device__ __forceinline__ float lrelu(float x) { return x > 0.f ? x : NEG_SLOPE * x; }
__device__ __forceinline__ float ldf(const void* p, int i, int bf) {
    return bf ? bf2f(((const u16*)p)[i]) : ((const float*)p)[i];
}
__device__ __forceinline__ int get_dst(const int* __restrict__ ei, int e, int ei64) {
    if (e < N_EDGES) return ei64 ? ei[2 * (N_EDGES + e)] : ei[N_EDGES + e];
    return e - N_EDGES;
}
__device__ __forceinline__ int get_src(const int* __restrict__ ei, int e, int ei64) {
    if (e < N_EDGES) return ei64 ? ei[2 * e] : ei[e];
    return e - N_EDGES;
}

// 8 bf16-channel FMA from one uint4 (16 B of an h row)
__device__ __forceinline__ void fma8(float wt, uint4 qv, float (&acc)[8]) {
    acc[0] = fmaf(wt, __uint_as_float(qv.x << 16), acc[0]);
    acc[1] = fmaf(wt, __uint_as_float(qv.x & 0xFFFF0000u), acc[1]);
    acc[2] = fmaf(wt, __uint_as_float(qv.y << 16), acc[2]);
    acc[3] = fmaf(wt, __uint_as_float(qv.y & 0xFFFF0000u), acc[3]);
    acc[4] = fmaf(wt, __uint_as_float(qv.z << 16), acc[4]);
    acc[5] = fmaf(wt, __uint_as_float(qv.z & 0xFFFF0000u), acc[5]);
    acc[6] = fmaf(wt, __uint_as_float(qv.w << 16), acc[6]);
    acc[7] = fmaf(wt, __uint_as_float(qv.w & 0xFFFF0000u), acc[7]);
}

// ---------------------------------------------------------------------------
// Detect input storage + zero bcnt (memset dispatch folded in).
// ---------------------------------------------------------------------------
__global__ void detect_kernel(const u32* __restrict__ x32, const int* __restrict__ ei,
                              int* __restrict__ flags, int* __restrict__ bcnt) {
    int lane = threadIdx.x;  // 64
    for (int i = lane; i < 256; i += 64) bcnt[i] = 0;
    u32 e = (x32[lane] >> 7) & 0xFFu;
    int ok = (e >= 96u && e <= 143u) ? 1 : 0;
    int cnt = (int)__popcll(__ballot(ok));
    int nz = (ei[2 * lane + 1] != 0) + (ei[2 * (lane + 64) + 1] != 0);
    #pragma unroll
    for (int off = 32; off > 0; off >>= 1) nz += __shfl_xor(nz, off);
    if (lane == 0) { flags[0] = (cnt >= 48) ? 1 : 0; flags[1] = (nz == 0) ? 1 : 0; }
}

// ---------------------------------------------------------------------------
// Pass 1: bin edges by dst>>9 into 196 buckets; code = (dst&511)<<17 | src.
// ---------------------------------------------------------------------------
__global__ __launch_bounds__(256) void bin_kernel(
    const int* __restrict__ ei, const int* __restrict__ flags,
    int* __restrict__ bcnt, u32* __restrict__ bbuf)
{
    __shared__ int hist[NBUCK];
    const int t = threadIdx.x;
    const int base = blockIdx.x * BINCH;
    const int ei64 = flags[1];
    for (int i = t; i < NBUCK; i += 256) hist[i] = 0;
    __syncthreads();

    int dloc[8], sloc[8];
    #pragma unroll
    for (int p = 0; p < 8; ++p) {
        int e = base + t + p * 256;
        if (e < ET) {
            dloc[p] = get_dst(ei, e, ei64);
            sloc[p] = get_src(ei, e, ei64);
            atomicAdd(&hist[dloc[p] >> BSHIFT], 1);
        } else {
            dloc[p] = -1; sloc[p] = 0;
        }
    }
    __syncthreads();
    for (int i = t; i < NBUCK; i += 256) {
        int c = hist[i];
        hist[i] = (c > 0) ? atomicAdd(&bcnt[i], c) : 0;
    }
    __syncthreads();
    #pragma unroll
    for (int p = 0; p < 8; ++p) {
        if (dloc[p] >= 0) {
            int b = dloc[p] >> BSHIFT;
            int pos = atomicAdd(&hist[b], 1);
            if (pos < BCAP)
                bbuf[(size_t)b * BCAP + pos] =
                    ((u32)(dloc[p] & (BW - 1)) << 17) | (u32)sloc[p];
        }
    }
}

// exclusive scan of clamped bucket counts -> bbase[NBUCK+1]
__global__ __launch_bounds__(256) void bscan_kernel(
    const int* __restrict__ bcnt, int* __restrict__ bbase)
{
    __shared__ int sd[256];
    int t = threadIdx.x;
    int v = (t < NBUCK) ? min(bcnt[t], BCAP) : 0;
    sd[t] = v;
    __syncthreads();
    for (int off = 1; off < 256; off <<= 1) {
        int x = (t >= off) ? sd[t - off] : 0;
        __syncthreads();
        sd[t] += x;
        __syncthreads();
    }
    if (t < NBUCK) bbase[t] = sd[t] - v;
    if (t == NBUCK - 1) bbase[NBUCK] = sd[t];
}

// ---------------------------------------------------------------------------
// Pass 2: one block (1024 threads) per bucket -> rowptr + dst-sorted ssrc.
// ---------------------------------------------------------------------------
__global__ __launch_bounds__(1024) void scatter_kernel(
    const int* __restrict__ bcnt, const int* __restrict__ bbase,
    const u32* __restrict__ bbuf, int* __restrict__ rowptr, int* __restrict__ ssrc)
{
    __shared__ int hist[BW];
    __shared__ int cur[BW];
    __shared__ int wtot[4];
    __shared__ int lds_s[BCAP];
    const int t = threadIdx.x;
    const int b = blockIdx.x;
    const int cnt = min(bcnt[b], BCAP);
    const int base = bbase[b];
    const u32* mybuf = bbuf + (size_t)b * BCAP;

    if (t < BW) hist[t] = 0;
    __syncthreads();
    for (int i = t; i < cnt; i += 1024) atomicAdd(&hist[(int)(mybuf[i] >> 17)], 1);
    __syncthreads();
    int a0 = 0, a1 = 0, s = 0, v = 0;
    const int lane = t & 63, wid = t >> 6;
    if (t < 256) {
        a0 = hist[2 * t]; a1 = hist[2 * t + 1];
        s = a0 + a1;
        v = s;
        #pragma unroll
        for (int off = 1; off < 64; off <<= 1) {
            int n = __shfl_up(v, off);
            if (lane >= off) v += n;
        }
        if (lane == 63) wtot[wid] = v;
    }
    __syncthreads();
    if (t == 0) {
        int acc = 0;
        #pragma unroll
        for (int w = 0; w < 4; ++w) { int tmp = wtot[w]; wtot[w] = acc; acc += tmp; }
    }
    __syncthreads();
    if (t < 256) {
        int excl = v + wtot[wid] - s;
        cur[2 * t] = excl;
        cur[2 * t + 1] = excl + a0;
    }
    __syncthreads();
    if (t < BW) {
        int g = b * BW + t;
        if (g < N_NODES) rowptr[g] = base + cur[t];
    }
    if (b == NBUCK - 1 && t == 0) rowptr[N_NODES] = bbase[NBUCK];
    __syncthreads();
    for (int i = t; i < cnt; i += 1024) {
        u32 code = mybuf[i];
        int pos = atomicAdd(&cur[(int)(code >> 17)], 1);
        lds_s[pos] = (int)(code & 0x1FFFFu);
    }
    __syncthreads();
    for (int i = t; i < cnt; i += 1024) ssrc[base + i] = lds_s[i];
}

// ---------------------------------------------------------------------------
// GEMM1: h[N,64](bf16) = x[N,128] @ W[128,64]; as_/ad_ score dots.
// ---------------------------------------------------------------------------
__global__ __launch_bounds__(256) void gemm1_kernel(
    const float* __restrict__ x, const float* __restrict__ W,
    const void* __restrict__ a_src, const void* __restrict__ a_dst,
    const int* __restrict__ flags,
    u16* __restrict__ h, float* __restrict__ as_, float* __restrict__ ad_)
{
    __shared__ float xs[256 * 33];   // 33.8 KB
    __shared__ float Wl[32 * 64];    // 8 KB
    const int t = threadIdx.x;
    const int node0 = blockIdx.x * 256;
    const int bf = flags[0];
    const int ng = t >> 3;
    const int cg = t & 7;

    float acc[8][8];
    #pragma unroll
    for (int i = 0; i < 8; ++i)
        #pragma unroll
        for (int j = 0; j < 8; ++j) acc[i][j] = 0.f;

    for (int kc = 0; kc < 4; ++kc) {
        const int kb = kc * 32;
        const int c4 = t & 7;
        #pragma unroll
        for (int p = 0; p < 8; ++p) {
            int row = (t >> 3) + p * 32;
            int n = node0 + row;
            float4 vv = make_float4(0.f, 0.f, 0.f, 0.f);
            if (n < N_NODES) {
                if (!bf) {
                    vv = *(const float4*)(x + (size_t)n * 128 + kb + c4 * 4);
                } else {
                    const u16* xh = (const u16*)x;
                    vv.x = bf2f(xh[(size_t)n * 128 + kb + c4 * 4 + 0]);
                    vv.y = bf2f(xh[(size_t)n * 128 + kb + c4 * 4 + 1]);
                    vv.z = bf2f(xh[(size_t)n * 128 + kb + c4 * 4 + 2]);
                    vv.w = bf2f(xh[(size_t)n * 128 + kb + c4 * 4 + 3]);
                }
            }
            float* dstp = &xs[row * 33 + c4 * 4];
            dstp[0] = vv.x; dstp[1] = vv.y; dstp[2] = vv.z; dstp[3] = vv.w;
        }
        if (!bf) {
            #pragma unroll
            for (int qq = 0; qq < 2; ++qq) {
                int f4 = t * 2 + qq;
                ((float4*)Wl)[f4] = ((const float4*)(W + (size_t)kb * 64))[f4];
            }
        } else {
            const u16* Wh = (const u16*)W;
            for (int i = t; i < 2048; i += 256) Wl[i] = bf2f(Wh[(size_t)kb * 64 + i]);
        }
        __syncthreads();

        for (int kk = 0; kk < 32; ++kk) {
            float xr[8];
            #pragma unroll
            for (int i = 0; i < 8; ++i) xr[i] = xs[(ng * 8 + i) * 33 + kk];
            float4 w0 = *(const float4*)&Wl[kk * 64 + cg * 8];
            float4 w1 = *(const float4*)&Wl[kk * 64 + cg * 8 + 4];
            const float wr[8] = {w0.x, w0.y, w0.z, w0.w, w1.x, w1.y, w1.z, w1.w};
            #pragma unroll
            for (int i = 0; i < 8; ++i)
                #pragma unroll
                for (int j = 0; j < 8; ++j)
                    acc[i][j] = fmaf(xr[i], wr[j], acc[i][j]);
        }
        __syncthreads();
    }

    float av[8], dv[8];
    #pragma unroll
    for (int j = 0; j < 8; ++j) {
        av[j] = ldf(a_src, cg * 8 + j, bf);
        dv[j] = ldf(a_dst, cg * 8 + j, bf);
    }
    #pragma unroll
    for (int i = 0; i < 8; ++i) {
        int n = node0 + ng * 8 + i;
        float ps = 0.f, pd = 0.f;
        #pragma unroll
        for (int j = 0; j < 8; ++j) { ps += acc[i][j] * av[j]; pd += acc[i][j] * dv[j]; }
        #pragma unroll
        for (int off = 1; off < 8; off <<= 1) {
            ps += __shfl_xor(ps, off);
            pd += __shfl_xor(pd, off);
        }
        if (n < N_NODES) {
            uint4 hv;
            hv.x = (u32)f2bf(acc[i][0]) | ((u32)f2bf(acc[i][1]) << 16);
            hv.y = (u32)f2bf(acc[i][2]) | ((u32)f2bf(acc[i][3]) << 16);
            hv.z = (u32)f2bf(acc[i][4]) | ((u32)f2bf(acc[i][5]) << 16);
            hv.w = (u32)f2bf(acc[i][6]) | ((u32)f2bf(acc[i][7]) << 16);
            *(uint4*)&h[(size_t)n * 64 + cg * 8] = hv;
            if (cg == 0) { as_[n] = ps; ad_[n] = pd; }
        }
    }
}

// ---------------------------------------------------------------------------
// Score kernel (layer 1 only, r7-proven): WAVE per dst (4 dsts/block).
// Coalesced ssrc load, one as_ gather, 12-shfl reduce, coalesced uint2
// store of {coef = ex/l, src<<7}. Keeps the softmax OUT of the fused
// gather (r9-r12 showed integrating it pushes the fused kernel to 72 VGPR
// -> 30% occupancy; the wexs-based gather runs at 32 VGPR / 75%).
// ---------------------------------------------------------------------------
__global__ __launch_bounds__(256) void score1_kernel(
    const int* __restrict__ rowptr, const int* __restrict__ ssrc,
    const float* __restrict__ as_, const float* __restrict__ ad_,
    uint2* __restrict__ wexs)
{
    const int lane = threadIdx.x & 63;
    const int dst = blockIdx.x * 4 + (threadIdx.x >> 6);
    if (dst >= N_NODES) return;
    const int beg = rowptr[dst], end = rowptr[dst + 1];
    const int deg = end - beg;
    const float add = ad_[dst];

    if (deg <= 64) {
        int j = beg + lane;
        bool valid = j < end;
        int sj = valid ? ssrc[j] : 0;
        float sc = valid ? lrelu(as_[sj] + add) : -1e30f;
        float m = sc;
        #pragma unroll
        for (int off = 32; off > 0; off >>= 1) m = fmaxf(m, __shfl_xor(m, off));
        float ex = __expf(sc - m);                // invalid lanes underflow to 0
        float l = ex;
        #pragma unroll
        for (int off = 32; off > 0; off >>= 1) l += __shfl_xor(l, off);
        if (valid)
            wexs[j] = make_uint2(__float_as_uint(ex / l), ((u32)sj) << 7);
    } else {
        // deg > 64 (~never): 2-pass running softmax, then write pass
        float m = -1e30f, l = 0.f;
        for (int base = beg; base < end; base += 64) {
            int j = base + lane;
            bool valid = j < end;
            float sc = valid ? lrelu(as_[ssrc[j]] + add) : -1e30f;
            float cm = sc;
            #pragma unroll
            for (int off = 32; off > 0; off >>= 1) cm = fmaxf(cm, __shfl_xor(cm, off));
            float nm = fmaxf(m, cm);
            float cs = __expf(sc - nm);
            #pragma unroll
            for (int off = 32; off > 0; off >>= 1) cs += __shfl_xor(cs, off);
            l = l * __expf(m - nm) + cs;
            m = nm;
        }
        float inv = 1.f / l;
        for (int base = beg; base < end; base += 64) {
            int j = base + lane;
            if (j < end) {
                int sj = ssrc[j];
                wexs[j] = make_uint2(
                    __float_as_uint(__expf(lrelu(as_[sj] + add) - m) * inv),
                    ((u32)sj) << 7);
            }
        }
    }
}

// ---------------------------------------------------------------------------
// Gather C=64 (wexs-based, r7-proven 32-VGPR body) + FUSED GEMM2 with the
// r9 conflict-free epilogue (linear W2s [k][c], b128 hin broadcast).
// r8 proved gather+epilogue fusion stays at 32 VGPR / 75% occ; r8's 24us
// epilogue overhead came from the transposed stride-66 W2 (1M conflicts,
// 64 serial b64 reads) — fixed here. Weights pre-normalized (coef=ex/l).
// ---------------------------------------------------------------------------
__global__ __launch_bounds__(256) void gather64_g2_kernel(
    const int* __restrict__ rowptr, const uint2* __restrict__ wexs,
    const u16* __restrict__ h, const void* __restrict__ b1,
    const u32* __restrict__ W32, const void* __restrict__ a_src2,
    const void* __restrict__ a_dst2, const int* __restrict__ flags,
    u16* __restrict__ h2, float* __restrict__ as2, float* __restrict__ ad2)
{
    __shared__ float W2s[64 * 32];       // 8 KB, row-major [k][c]
    __shared__ float hin_lds[8 * 64];    // 2 KB, per half-wave hin
    const int tid = threadIdx.x;
    const int hl = tid & 31;                      // lane within half-wave
    const int dreal = blockIdx.x * 8 + (tid >> 5);
    const int dst = min(dreal, N_NODES - 1);
    const int bf = flags[0];

    // stage W2 linear f32 (coalesced, conflict-free)
    if (bf) {
        for (int i = tid; i < 1024; i += 256) {
            u32 u = W32[i];
            *(float2*)&W2s[2 * i] = make_float2(__uint_as_float(u << 16),
                                                __uint_as_float(u & 0xFFFF0000u));
        }
    } else {
        for (int i = tid; i < 2048; i += 256) W2s[i] = __uint_as_float(W32[i]);
    }
    __syncthreads();

    const int beg = rowptr[dst];
    const int deg = rowptr[dst + 1] - beg;
    const int e4 = hl >> 3;                       // edge slot in group (0..3)
    const int i8 = hl & 7;                        // uint4 index in 128B row
    const char* __restrict__ hb = (const char*)h;
    const u32 boff = (u32)(i8 * 16);

    float acc[8] = {0.f, 0.f, 0.f, 0.f, 0.f, 0.f, 0.f, 0.f};

    #pragma unroll
    for (int g = 0; g < 8; ++g) {
        int eidx = g * 4 + e4;
        bool valid = eidx < deg;
        uint2 p = wexs[beg + (valid ? eidx : 0)];
        float w = valid ? __uint_as_float(p.x) : 0.f;
        uint4 qv = *(const uint4*)(hb + (size_t)(p.y + boff));
        fma8(w, qv, acc);
    }
    int mdeg = max(deg, __shfl_xor(deg, 32));     // wave-uniform
    for (int g = 8; g * 4 < mdeg; ++g) {          // rare (deg > 32)
        int eidx = g * 4 + e4;
        bool valid = eidx < deg;
        uint2 p = wexs[beg + (valid ? eidx : 0)];
        float w = valid ? __uint_as_float(p.x) : 0.f;
        uint4 qv = *(const uint4*)(hb + (size_t)(p.y + boff));
        fma8(w, qv, acc);
    }

    // reduce across 4 edge-slots; every lane then holds channels i8*8..+7
    #pragma unroll
    for (int c = 0; c < 8; ++c) {
        acc[c] += __shfl_xor(acc[c], 8);
        acc[c] += __shfl_xor(acc[c], 16);
    }

    // ---- fused gemm2 epilogue (conflict-free) ----
    float* hin_s = &hin_lds[(tid >> 5) * 64];     // per half-wave region
    if (hl < 8) {
        float4 v0, v1;
        v0.x = fmaxf(acc[0] + ldf(b1, hl * 8 + 0, bf), 0.f);
        v0.y = fmaxf(acc[1] + ldf(b1, hl * 8 + 1, bf), 0.f);
        v0.z = fmaxf(acc[2] + ldf(b1, hl * 8 + 2, bf), 0.f);
        v0.w = fmaxf(acc[3] + ldf(b1, hl * 8 + 3, bf), 0.f);
        v1.x = fmaxf(acc[4] + ldf(b1, hl * 8 + 4, bf), 0.f);
        v1.y = fmaxf(acc[5] + ldf(b1, hl * 8 + 5, bf), 0.f);
        v1.z = fmaxf(acc[6] + ldf(b1, hl * 8 + 6, bf), 0.f);
        v1.w = fmaxf(acc[7] + ldf(b1, hl * 8 + 7, bf), 0.f);
        *(float4*)&hin_s[hl * 8] = v0;
        *(float4*)&hin_s[hl * 8 + 4] = v1;
    }
    __builtin_amdgcn_wave_barrier();
    asm volatile("s_waitcnt lgkmcnt(0)" ::: "memory");

    // matvec: lane hl = output channel. hin = b128 broadcast; W2s per-k reads
    // are 32 consecutive dwords across the half-wave (conflict-free).
    float o = 0.f;
    #pragma unroll 16
    for (int k = 0; k < 64; k += 4) {
        float4 hv = *(const float4*)&hin_s[k];
        o = fmaf(hv.x, W2s[(k + 0) * 32 + hl], o);
        o = fmaf(hv.y, W2s[(k + 1) * 32 + hl], o);
        o = fmaf(hv.z, W2s[(k + 2) * 32 + hl], o);
        o = fmaf(hv.w, W2s[(k + 3) * 32 + hl], o);
    }

    float ps = o * ldf(a_src2, hl, bf);
    float pd = o * ldf(a_dst2, hl, bf);
    #pragma unroll
    for (int off = 1; off < 32; off <<= 1) {
        ps += __shfl_xor(ps, off);
        pd += __shfl_xor(pd, off);
    }
    u32 hbits = (u32)f2bf(o);
    u32 other = (u32)__shfl_xor((int)hbits, 1);
    if (dreal < N_NODES) {
        if ((hl & 1) == 0)
            *((u32*)h2 + (size_t)dst * 16 + (hl >> 1)) = hbits | (other << 16);
        if (hl == 0) { as2[dst] = ps; ad2[dst] = pd; }
    }
    __builtin_amdgcn_wave_barrier();   // hin_s reads precede any reuse
}

// ---------------------------------------------------------------------------
// Gather C=32 + integrated defer-normalized softmax + fused bias/log_softmax
// (unchanged from r12 — runs below the visibility cutoff; no gemm epilogue
// so its register pressure is acceptable).
// ---------------------------------------------------------------------------
__global__ __launch_bounds__(256) void gather32_lsm_kernel(
    const int* __restrict__ rowptr, const int* __restrict__ ssrc,
    const float* __restrict__ as_, const float* __restrict__ ad_,
    const u16* __restrict__ h, const void* __restrict__ b2,
    const int* __restrict__ flags, float* __restrict__ out)
{
    const int tid = threadIdx.x;
    const int hl = tid & 31;
    const int hbase = tid & 32;
    const int dreal = blockIdx.x * 8 + (tid >> 5);
    const int dst = min(dreal, N_NODES - 1);
    const int beg = rowptr[dst];
    const int end = rowptr[dst + 1];
    const float add = ad_[dst];
    const int e8 = hl >> 2;                       // edge slot in group (0..7)
    const int i4 = hl & 3;                        // uint4 index in 64B row
    const int bf = flags[0];
    const char* __restrict__ hb = (const char*)h;
    const u32 boff = (u32)(i4 * 16);

    float acc[8] = {0.f, 0.f, 0.f, 0.f, 0.f, 0.f, 0.f, 0.f};
    float lacc = 0.f;

    for (int eb = beg; eb < end; eb += 32) {
        int j = eb + hl;
        bool valid = j < end;
        int sj = valid ? ssrc[j] : 0;
        float asv = as_[sj];
        int rowoff = sj << 6;
        float sc = valid ? lrelu(asv + add) : -1e30f;
        float ex = __expf(sc);
        lacc += ex;

        {   // edges eb+0..15 (groups 0,1)
            int l0 = hbase + e8;
            int l1 = hbase + 8 + e8;
            int ga0 = __shfl(rowoff, l0);
            int ga1 = __shfl(rowoff, l1);
            uint4 q0 = *(const uint4*)(hb + (size_t)((u32)ga0 + boff));
            uint4 q1 = *(const uint4*)(hb + (size_t)((u32)ga1 + boff));
            float w0 = __shfl(ex, l0);
            float w1 = __shfl(ex, l1);
            fma8(w0, q0, acc); fma8(w1, q1, acc);
        }
        if (end - eb > 16) {   // edges eb+16..31 (groups 2,3)
            int l2 = hbase + 16 + e8;
            int l3 = hbase + 24 + e8;
            int ga2 = __shfl(rowoff, l2);
            int ga3 = __shfl(rowoff, l3);
            uint4 q2 = *(const uint4*)(hb + (size_t)((u32)ga2 + boff));
            uint4 q3 = *(const uint4*)(hb + (size_t)((u32)ga3 + boff));
            float w2 = __shfl(ex, l2);
            float w3 = __shfl(ex, l3);
            fma8(w2, q2, acc); fma8(w3, q3, acc);
        }
    }

    #pragma unroll
    for (int off = 16; off > 0; off >>= 1) lacc += __shfl_xor(lacc, off);
    float invl = 1.f / lacc;

    // reduce across 8 edge-slots (stride 4; stays within 32-lane half)
    #pragma unroll
    for (int c = 0; c < 8; ++c) {
        acc[c] += __shfl_xor(acc[c], 4);
        acc[c] += __shfl_xor(acc[c], 8);
        acc[c] += __shfl_xor(acc[c], 16);
    }

    // fused bias + log_softmax: quad lanes (i4) x 8 channels
    float v[8];
    #pragma unroll
    for (int c = 0; c < 8; ++c) v[c] = fmaf(acc[c], invl, ldf(b2, i4 * 8 + c, bf));
    float mx = v[0];
    #pragma unroll
    for (int c = 1; c < 8; ++c) mx = fmaxf(mx, v[c]);
    mx = fmaxf(mx, __shfl_xor(mx, 1));
    mx = fmaxf(mx, __shfl_xor(mx, 2));
    float ss = 0.f;
    #pragma unroll
    for (int c = 0; c < 8; ++c) ss += __expf(v[c] - mx);
    ss += __shfl_xor(ss, 1);
    ss += __shfl_xor(ss, 2);
    float lg = mx + __logf(ss);
    if (e8 == 0 && dreal < N_NODES) {
        *(float4*)&out[(size_t)dst * 32 + i4 * 8] =
            make_float4(v[0] - lg, v[1] - lg, v[2] - lg, v[3] - lg);
        *(float4*)&out[(size_t)dst * 32 + i4 * 8 + 4] =
            make_float4(v[4] - lg, v[5] - lg, v[6] - lg, v[7] - lg);
    }
}

// ---------------------------------------------------------------------------
extern "C" void kernel_launch(void* const* d_in, const int* in_sizes, int n_in,
                              void* d_out, int out_size, void* d_ws, size_t ws_size,
                              hipStream_t stream) {
    const float* x   = (const float*)d_in[0];
    const int* ei    = (const int*)d_in[1];
    const float* W1  = (const float*)d_in[2];
    const void* a_s1 = d_in[3];
    const void* a_d1 = d_in[4];
    const void* b1   = d_in[5];
    const u32* W2    = (const u32*)d_in[6];
    const void* a_s2 = d_in[7];
    const void* a_d2 = d_in[8];
    const void* b2   = d_in[9];
    float* out = (float*)d_out;

    // workspace carve-up (~61 MB). bbuf/wexs alias at the END (bbuf dead
    // after scatter; wexs = 13.6 MB uint2 per edge, layer 1 only).
    char* base = (char*)d_ws;
    int* flags = (int*)base;
    u16* h     = (u16*)(base + 64);                           // N*64 bf16 (layer-1)
    char* q = base + 64 + (size_t)N_NODES * 64 * 2;
    float* as1 = (float*)q; q += (size_t)N_NODES * 4;
    float* ad1 = (float*)q; q += (size_t)N_NODES * 4;
    float* as2 = (float*)q; q += (size_t)N_NODES * 4;
    float* ad2 = (float*)q; q += (size_t)N_NODES * 4;
    u16* h2    = (u16*)q;   q += (size_t)N_NODES * 32 * 2;    // N*32 bf16 (layer-2)
    int* rowptr = (int*)q;  q += (size_t)(N_NODES + 16) * 4;
    int* ssrc   = (int*)q;  q += (size_t)ET * 4;
    int* bcnt   = (int*)q;  q += 256 * 4;
    int* bbase  = (int*)q;  q += 256 * 4;
    q = (char*)(((size_t)q + 255) & ~(size_t)255);            // align 256
    u32*  bbuf  = (u32*)q;                                    // 8.03 MB (sort only)
    uint2* wexs = (uint2*)q;                                  // 13.6 MB, aliases bbuf

    detect_kernel<<<1, 64, 0, stream>>>((const u32*)x, ei, flags, bcnt);

    // CSR by dst via 2-pass bucket sort (rowptr built in scatter)
    bin_kernel<<<(ET + BINCH - 1) / BINCH, 256, 0, stream>>>(ei, flags, bcnt, bbuf);
    bscan_kernel<<<1, 256, 0, stream>>>(bcnt, bbase);
    scatter_kernel<<<NBUCK, 1024, 0, stream>>>(bcnt, bbase, bbuf, rowptr, ssrc);

    // layer 1: gemm -> score (softmax out of the fused kernel) -> gather+gemm2
    gemm1_kernel<<<(N_NODES + 255) / 256, 256, 0, stream>>>(x, W1, a_s1, a_d1, flags, h, as1, ad1);
    score1_kernel<<<(N_NODES + 3) / 4, 256, 0, stream>>>(rowptr, ssrc, as1, ad1, wexs);
    gather64_g2_kernel<<<(N_NODES + 7) / 8, 256, 0, stream>>>(
        rowptr, wexs, h, b1, W2, a_s2, a_d2, flags, h2, as2, ad2);

    // layer 2 (integrated softmax; lsm fused; writes d_out directly)
    gather32_lsm_kernel<<<(N_NODES + 7) / 8, 256, 0, stream>>>(
        rowptr, ssrc, as2, ad2, h2, b2, flags, out);
}

// Round 14
// 278.012 us; speedup vs baseline: 1.2427x; 1.2427x over previous
//
#include <hip/hip_runtime.h>

#define N_NODES 100000
#define N_EDGES 1600000
#define ET (N_EDGES + N_NODES)
#define NEG_SLOPE 0.2f

// bucket sort params
#define BSHIFT 9
#define BW 512                                  // nodes per bucket
#define NBUCK ((N_NODES + BW - 1) / BW)         // 196
#define BCAP 10240
#define BINCH 2048                              // edges per bin block

typedef unsigned short u16;
typedef unsigned int u32;

__device__ __forceinline__ float bf2f(u16 v) {
    return __uint_as_float(((u32)v) << 16);
}
__device__ __forceinline__ u16 f2bf(float f) {
    u32 u = __float_as_uint(f);
    u32 r = (u + 0x7FFFu + ((u >> 16) & 1u)) >> 16;  // RNE
    return (u16)r;
}
__device__ __forceinline__ float lrelu(float x) { return x > 0.f ? x : NEG_SLOPE * x; }
__device__ __forceinline__ float ldf(const void* p, int i, int bf) {
    return bf ? bf2f(((const u16*)p)[i]) : ((const float*)p)[i];
}
__device__ __forceinline__ int get_dst(const int* __restrict__ ei, int e, int ei64) {
    if (e < N_EDGES) return ei64 ? ei[2 * (N_EDGES + e)] : ei[N_EDGES + e];
    return e - N_EDGES;
}
__device__ __forceinline__ int get_src(const int* __restrict__ ei, int e, int ei64) {
    if (e < N_EDGES) return ei64 ? ei[2 * e] : ei[e];
    return e - N_EDGES;
}

// 8 bf16-channel FMA from one uint4 (16 B of an h row)
__device__ __forceinline__ void fma8(float wt, uint4 qv, float (&acc)[8]) {
    acc[0] = fmaf(wt, __uint_as_float(qv.x << 16), acc[0]);
    acc[1] = fmaf(wt, __uint_as_float(qv.x & 0xFFFF0000u), acc[1]);
    acc[2] = fmaf(wt, __uint_as_float(qv.y << 16), acc[2]);
    acc[3] = fmaf(wt, __uint_as_float(qv.y & 0xFFFF0000u), acc[3]);
    acc[4] = fmaf(wt, __uint_as_float(qv.z << 16), acc[4]);
    acc[5] = fmaf(wt, __uint_as_float(qv.z & 0xFFFF0000u), acc[5]);
    acc[6] = fmaf(wt, __uint_as_float(qv.w << 16), acc[6]);
    acc[7] = fmaf(wt, __uint_as_float(qv.w & 0xFFFF0000u), acc[7]);
}

// ---------------------------------------------------------------------------
// Detect input storage + zero bcnt (memset dispatch folded in).
// ---------------------------------------------------------------------------
__global__ void detect_kernel(const u32* __restrict__ x32, const int* __restrict__ ei,
                              int* __restrict__ flags, int* __restrict__ bcnt) {
    int lane = threadIdx.x;  // 64
    for (int i = lane; i < 256; i += 64) bcnt[i] = 0;
    u32 e = (x32[lane] >> 7) & 0xFFu;
    int ok = (e >= 96u && e <= 143u) ? 1 : 0;
    int cnt = (int)__popcll(__ballot(ok));
    int nz = (ei[2 * lane + 1] != 0) + (ei[2 * (lane + 64) + 1] != 0);
    #pragma unroll
    for (int off = 32; off > 0; off >>= 1) nz += __shfl_xor(nz, off);
    if (lane == 0) { flags[0] = (cnt >= 48) ? 1 : 0; flags[1] = (nz == 0) ? 1 : 0; }
}

// ---------------------------------------------------------------------------
// Pass 1: bin edges by dst>>9 into 196 buckets; code = (dst&511)<<17 | src.
// ---------------------------------------------------------------------------
__global__ __launch_bounds__(256) void bin_kernel(
    const int* __restrict__ ei, const int* __restrict__ flags,
    int* __restrict__ bcnt, u32* __restrict__ bbuf)
{
    __shared__ int hist[NBUCK];
    const int t = threadIdx.x;
    const int base = blockIdx.x * BINCH;
    const int ei64 = flags[1];
    for (int i = t; i < NBUCK; i += 256) hist[i] = 0;
    __syncthreads();

    int dloc[8], sloc[8];
    #pragma unroll
    for (int p = 0; p < 8; ++p) {
        int e = base + t + p * 256;
        if (e < ET) {
            dloc[p] = get_dst(ei, e, ei64);
            sloc[p] = get_src(ei, e, ei64);
            atomicAdd(&hist[dloc[p] >> BSHIFT], 1);
        } else {
            dloc[p] = -1; sloc[p] = 0;
        }
    }
    __syncthreads();
    for (int i = t; i < NBUCK; i += 256) {
        int c = hist[i];
        hist[i] = (c > 0) ? atomicAdd(&bcnt[i], c) : 0;
    }
    __syncthreads();
    #pragma unroll
    for (int p = 0; p < 8; ++p) {
        if (dloc[p] >= 0) {
            int b = dloc[p] >> BSHIFT;
            int pos = atomicAdd(&hist[b], 1);
            if (pos < BCAP)
                bbuf[(size_t)b * BCAP + pos] =
                    ((u32)(dloc[p] & (BW - 1)) << 17) | (u32)sloc[p];
        }
    }
}

// exclusive scan of clamped bucket counts -> bbase[NBUCK+1]
__global__ __launch_bounds__(256) void bscan_kernel(
    const int* __restrict__ bcnt, int* __restrict__ bbase)
{
    __shared__ int sd[256];
    int t = threadIdx.x;
    int v = (t < NBUCK) ? min(bcnt[t], BCAP) : 0;
    sd[t] = v;
    __syncthreads();
    for (int off = 1; off < 256; off <<= 1) {
        int x = (t >= off) ? sd[t - off] : 0;
        __syncthreads();
        sd[t] += x;
        __syncthreads();
    }
    if (t < NBUCK) bbase[t] = sd[t] - v;
    if (t == NBUCK - 1) bbase[NBUCK] = sd[t];
}

// ---------------------------------------------------------------------------
// Pass 2: one block (1024 threads) per bucket -> rowptr + dst-sorted ssrc.
// ---------------------------------------------------------------------------
__global__ __launch_bounds__(1024) void scatter_kernel(
    const int* __restrict__ bcnt, const int* __restrict__ bbase,
    const u32* __restrict__ bbuf, int* __restrict__ rowptr, int* __restrict__ ssrc)
{
    __shared__ int hist[BW];
    __shared__ int cur[BW];
    __shared__ int wtot[4];
    __shared__ int lds_s[BCAP];
    const int t = threadIdx.x;
    const int b = blockIdx.x;
    const int cnt = min(bcnt[b], BCAP);
    const int base = bbase[b];
    const u32* mybuf = bbuf + (size_t)b * BCAP;

    if (t < BW) hist[t] = 0;
    __syncthreads();
    for (int i = t; i < cnt; i += 1024) atomicAdd(&hist[(int)(mybuf[i] >> 17)], 1);
    __syncthreads();
    int a0 = 0, a1 = 0, s = 0, v = 0;
    const int lane = t & 63, wid = t >> 6;
    if (t < 256) {
        a0 = hist[2 * t]; a1 = hist[2 * t + 1];
        s = a0 + a1;
        v = s;
        #pragma unroll
        for (int off = 1; off < 64; off <<= 1) {
            int n = __shfl_up(v, off);
            if (lane >= off) v += n;
        }
        if (lane == 63) wtot[wid] = v;
    }
    __syncthreads();
    if (t == 0) {
        int acc = 0;
        #pragma unroll
        for (int w = 0; w < 4; ++w) { int tmp = wtot[w]; wtot[w] = acc; acc += tmp; }
    }
    __syncthreads();
    if (t < 256) {
        int excl = v + wtot[wid] - s;
        cur[2 * t] = excl;
        cur[2 * t + 1] = excl + a0;
    }
    __syncthreads();
    if (t < BW) {
        int g = b * BW + t;
        if (g < N_NODES) rowptr[g] = base + cur[t];
    }
    if (b == NBUCK - 1 && t == 0) rowptr[N_NODES] = bbase[NBUCK];
    __syncthreads();
    for (int i = t; i < cnt; i += 1024) {
        u32 code = mybuf[i];
        int pos = atomicAdd(&cur[(int)(code >> 17)], 1);
        lds_s[pos] = (int)(code & 0x1FFFFu);
    }
    __syncthreads();
    for (int i = t; i < cnt; i += 1024) ssrc[base + i] = lds_s[i];
}

// ---------------------------------------------------------------------------
// GEMM1: h[N,64](bf16) = x[N,128] @ W[128,64]; as_/ad_ score dots.
// ---------------------------------------------------------------------------
__global__ __launch_bounds__(256) void gemm1_kernel(
    const float* __restrict__ x, const float* __restrict__ W,
    const void* __restrict__ a_src, const void* __restrict__ a_dst,
    const int* __restrict__ flags,
    u16* __restrict__ h, float* __restrict__ as_, float* __restrict__ ad_)
{
    __shared__ float xs[256 * 33];   // 33.8 KB
    __shared__ float Wl[32 * 64];    // 8 KB
    const int t = threadIdx.x;
    const int node0 = blockIdx.x * 256;
    const int bf = flags[0];
    const int ng = t >> 3;
    const int cg = t & 7;

    float acc[8][8];
    #pragma unroll
    for (int i = 0; i < 8; ++i)
        #pragma unroll
        for (int j = 0; j < 8; ++j) acc[i][j] = 0.f;

    for (int kc = 0; kc < 4; ++kc) {
        const int kb = kc * 32;
        const int c4 = t & 7;
        #pragma unroll
        for (int p = 0; p < 8; ++p) {
            int row = (t >> 3) + p * 32;
            int n = node0 + row;
            float4 vv = make_float4(0.f, 0.f, 0.f, 0.f);
            if (n < N_NODES) {
                if (!bf) {
                    vv = *(const float4*)(x + (size_t)n * 128 + kb + c4 * 4);
                } else {
                    const u16* xh = (const u16*)x;
                    vv.x = bf2f(xh[(size_t)n * 128 + kb + c4 * 4 + 0]);
                    vv.y = bf2f(xh[(size_t)n * 128 + kb + c4 * 4 + 1]);
                    vv.z = bf2f(xh[(size_t)n * 128 + kb + c4 * 4 + 2]);
                    vv.w = bf2f(xh[(size_t)n * 128 + kb + c4 * 4 + 3]);
                }
            }
            float* dstp = &xs[row * 33 + c4 * 4];
            dstp[0] = vv.x; dstp[1] = vv.y; dstp[2] = vv.z; dstp[3] = vv.w;
        }
        if (!bf) {
            #pragma unroll
            for (int qq = 0; qq < 2; ++qq) {
                int f4 = t * 2 + qq;
                ((float4*)Wl)[f4] = ((const float4*)(W + (size_t)kb * 64))[f4];
            }
        } else {
            const u16* Wh = (const u16*)W;
            for (int i = t; i < 2048; i += 256) Wl[i] = bf2f(Wh[(size_t)kb * 64 + i]);
        }
        __syncthreads();

        for (int kk = 0; kk < 32; ++kk) {
            float xr[8];
            #pragma unroll
            for (int i = 0; i < 8; ++i) xr[i] = xs[(ng * 8 + i) * 33 + kk];
            float4 w0 = *(const float4*)&Wl[kk * 64 + cg * 8];
            float4 w1 = *(const float4*)&Wl[kk * 64 + cg * 8 + 4];
            const float wr[8] = {w0.x, w0.y, w0.z, w0.w, w1.x, w1.y, w1.z, w1.w};
            #pragma unroll
            for (int i = 0; i < 8; ++i)
                #pragma unroll
                for (int j = 0; j < 8; ++j)
                    acc[i][j] = fmaf(xr[i], wr[j], acc[i][j]);
        }
        __syncthreads();
    }

    float av[8], dv[8];
    #pragma unroll
    for (int j = 0; j < 8; ++j) {
        av[j] = ldf(a_src, cg * 8 + j, bf);
        dv[j] = ldf(a_dst, cg * 8 + j, bf);
    }
    #pragma unroll
    for (int i = 0; i < 8; ++i) {
        int n = node0 + ng * 8 + i;
        float ps = 0.f, pd = 0.f;
        #pragma unroll
        for (int j = 0; j < 8; ++j) { ps += acc[i][j] * av[j]; pd += acc[i][j] * dv[j]; }
        #pragma unroll
        for (int off = 1; off < 8; off <<= 1) {
            ps += __shfl_xor(ps, off);
            pd += __shfl_xor(pd, off);
        }
        if (n < N_NODES) {
            uint4 hv;
            hv.x = (u32)f2bf(acc[i][0]) | ((u32)f2bf(acc[i][1]) << 16);
            hv.y = (u32)f2bf(acc[i][2]) | ((u32)f2bf(acc[i][3]) << 16);
            hv.z = (u32)f2bf(acc[i][4]) | ((u32)f2bf(acc[i][5]) << 16);
            hv.w = (u32)f2bf(acc[i][6]) | ((u32)f2bf(acc[i][7]) << 16);
            *(uint4*)&h[(size_t)n * 64 + cg * 8] = hv;
            if (cg == 0) { as_[n] = ps; ad_[n] = pd; }
        }
    }
}

// ---------------------------------------------------------------------------
// Gather C=64 + integrated defer-normalized softmax + FUSED GEMM2 (r14).
// r13 isolated the register hog: the fully-unrolled epilogue matvec
// (#pragma unroll 16) hoists 16 float4 hin loads + 64 W2s loads => ~40
// extra live VGPRs => 72 total => 30% occupancy in EVERY r9-r13 variant.
// The gather+softmax body alone is ~32 VGPR (r5/r7). r14 = r12 body +
// epilogue capped at unroll 2 (2 float4 hin + 8 W2s live ≈ 16 regs).
// Target: natural alloc <= 64 -> 8 waves/SIMD.
// ---------------------------------------------------------------------------
__global__ __launch_bounds__(256) void gather64_g2_kernel(
    const int* __restrict__ rowptr, const int* __restrict__ ssrc,
    const float* __restrict__ as_, const float* __restrict__ ad_,
    const u16* __restrict__ h, const void* __restrict__ b1,
    const u32* __restrict__ W32, const void* __restrict__ a_src2,
    const void* __restrict__ a_dst2, const int* __restrict__ flags,
    u16* __restrict__ h2, float* __restrict__ as2, float* __restrict__ ad2)
{
    __shared__ float W2s[64 * 32];       // 8 KB, row-major [k][c]
    __shared__ float hin_lds[8 * 64];    // 2 KB, per half-wave hin
    const int tid = threadIdx.x;
    const int hl = tid & 31;                      // lane within half-wave
    const int hbase = tid & 32;                   // absolute base lane of half
    const int dreal = blockIdx.x * 8 + (tid >> 5);
    const int dst = min(dreal, N_NODES - 1);
    const int bf = flags[0];

    // early dst loads (complete during W2 staging)
    const int beg = rowptr[dst];
    const int end = rowptr[dst + 1];
    const float add = ad_[dst];

    // stage W2 linear f32 (coalesced, conflict-free)
    if (bf) {
        for (int i = tid; i < 1024; i += 256) {
            u32 u = W32[i];
            *(float2*)&W2s[2 * i] = make_float2(__uint_as_float(u << 16),
                                                __uint_as_float(u & 0xFFFF0000u));
        }
    } else {
        for (int i = tid; i < 2048; i += 256) W2s[i] = __uint_as_float(W32[i]);
    }
    __syncthreads();

    const int e4 = hl >> 3;                       // edge slot in group (0..3)
    const int i8 = hl & 7;                        // uint4 index in 128B row
    const char* __restrict__ hb = (const char*)h;
    const u32 boff = (u32)(i8 * 16);

    float acc[8] = {0.f, 0.f, 0.f, 0.f, 0.f, 0.f, 0.f, 0.f};
    float lacc = 0.f;

    for (int eb = beg; eb < end; eb += 32) {
        int j = eb + hl;
        bool valid = j < end;
        int sj = valid ? ssrc[j] : 0;
        float asv = as_[sj];
        int rowoff = sj << 7;
        float sc = valid ? lrelu(asv + add) : -1e30f;
        float ex = __expf(sc);                    // invalid -> 0
        lacc += ex;

        #pragma unroll
        for (int gg = 0; gg < 2; ++gg) {          // groups 0..3: edges eb..eb+15
            int l0 = hbase + (gg * 2) * 4 + e4;
            int l1 = hbase + (gg * 2 + 1) * 4 + e4;
            int ga0 = __shfl(rowoff, l0);
            int ga1 = __shfl(rowoff, l1);
            uint4 q0 = *(const uint4*)(hb + (size_t)((u32)ga0 + boff));
            uint4 q1 = *(const uint4*)(hb + (size_t)((u32)ga1 + boff));
            float w0 = __shfl(ex, l0);
            float w1 = __shfl(ex, l1);
            fma8(w0, q0, acc); fma8(w1, q1, acc);
        }
        if (end - eb > 16) {                      // groups 4..7: edges eb+16..31
            #pragma unroll
            for (int gg = 2; gg < 4; ++gg) {
                int l0 = hbase + (gg * 2) * 4 + e4;
                int l1 = hbase + (gg * 2 + 1) * 4 + e4;
                int ga0 = __shfl(rowoff, l0);
                int ga1 = __shfl(rowoff, l1);
                uint4 q0 = *(const uint4*)(hb + (size_t)((u32)ga0 + boff));
                uint4 q1 = *(const uint4*)(hb + (size_t)((u32)ga1 + boff));
                float w0 = __shfl(ex, l0);
                float w1 = __shfl(ex, l1);
                fma8(w0, q0, acc); fma8(w1, q1, acc);
            }
        }
    }

    // denominator: one half-wave reduce, OFF the FMA critical path
    #pragma unroll
    for (int off = 16; off > 0; off >>= 1) lacc += __shfl_xor(lacc, off);
    float invl = 1.f / lacc;

    // reduce across 4 edge-slots; every lane then holds channels i8*8..+7
    #pragma unroll
    for (int c = 0; c < 8; ++c) {
        acc[c] += __shfl_xor(acc[c], 8);
        acc[c] += __shfl_xor(acc[c], 16);
    }

    // ---- fused gemm2 epilogue (normalize folded in) ----
    float* hin_s = &hin_lds[(tid >> 5) * 64];     // per half-wave region
    if (hl < 8) {
        float4 v0, v1;
        v0.x = fmaxf(fmaf(acc[0], invl, ldf(b1, hl * 8 + 0, bf)), 0.f);
        v0.y = fmaxf(fmaf(acc[1], invl, ldf(b1, hl * 8 + 1, bf)), 0.f);
        v0.z = fmaxf(fmaf(acc[2], invl, ldf(b1, hl * 8 + 2, bf)), 0.f);
        v0.w = fmaxf(fmaf(acc[3], invl, ldf(b1, hl * 8 + 3, bf)), 0.f);
        v1.x = fmaxf(fmaf(acc[4], invl, ldf(b1, hl * 8 + 4, bf)), 0.f);
        v1.y = fmaxf(fmaf(acc[5], invl, ldf(b1, hl * 8 + 5, bf)), 0.f);
        v1.z = fmaxf(fmaf(acc[6], invl, ldf(b1, hl * 8 + 6, bf)), 0.f);
        v1.w = fmaxf(fmaf(acc[7], invl, ldf(b1, hl * 8 + 7, bf)), 0.f);
        *(float4*)&hin_s[hl * 8] = v0;
        *(float4*)&hin_s[hl * 8 + 4] = v1;
    }
    __builtin_amdgcn_wave_barrier();
    asm volatile("s_waitcnt lgkmcnt(0)" ::: "memory");

    // matvec: lane hl = output channel. UNROLL CAPPED AT 2 (r14): full
    // unroll hoisted 16 float4 hin loads -> ~40 extra VGPRs -> 30% occ.
    float o = 0.f;
    #pragma unroll 2
    for (int k = 0; k < 64; k += 4) {
        float4 hv = *(const float4*)&hin_s[k];
        o = fmaf(hv.x, W2s[(k + 0) * 32 + hl], o);
        o = fmaf(hv.y, W2s[(k + 1) * 32 + hl], o);
        o = fmaf(hv.z, W2s[(k + 2) * 32 + hl], o);
        o = fmaf(hv.w, W2s[(k + 3) * 32 + hl], o);
    }

    float ps = o * ldf(a_src2, hl, bf);
    float pd = o * ldf(a_dst2, hl, bf);
    #pragma unroll
    for (int off = 1; off < 32; off <<= 1) {
        ps += __shfl_xor(ps, off);
        pd += __shfl_xor(pd, off);
    }
    u32 hbits = (u32)f2bf(o);
    u32 other = (u32)__shfl_xor((int)hbits, 1);
    if (dreal < N_NODES) {
        if ((hl & 1) == 0)
            *((u32*)h2 + (size_t)dst * 16 + (hl >> 1)) = hbits | (other << 16);
        if (hl == 0) { as2[dst] = ps; ad2[dst] = pd; }
    }
    __builtin_amdgcn_wave_barrier();   // hin_s reads precede any reuse
}

// ---------------------------------------------------------------------------
// Gather C=32 + integrated defer-normalized softmax + fused bias/log_softmax
// (unchanged from r12).
// ---------------------------------------------------------------------------
__global__ __launch_bounds__(256) void gather32_lsm_kernel(
    const int* __restrict__ rowptr, const int* __restrict__ ssrc,
    const float* __restrict__ as_, const float* __restrict__ ad_,
    const u16* __restrict__ h, const void* __restrict__ b2,
    const int* __restrict__ flags, float* __restrict__ out)
{
    const int tid = threadIdx.x;
    const int hl = tid & 31;
    const int hbase = tid & 32;
    const int dreal = blockIdx.x * 8 + (tid >> 5);
    const int dst = min(dreal, N_NODES - 1);
    const int beg = rowptr[dst];
    const int end = rowptr[dst + 1];
    const float add = ad_[dst];
    const int e8 = hl >> 2;                       // edge slot in group (0..7)
    const int i4 = hl & 3;                        // uint4 index in 64B row
    const int bf = flags[0];
    const char* __restrict__ hb = (const char*)h;
    const u32 boff = (u32)(i4 * 16);

    float acc[8] = {0.f, 0.f, 0.f, 0.f, 0.f, 0.f, 0.f, 0.f};
    float lacc = 0.f;

    for (int eb = beg; eb < end; eb += 32) {
        int j = eb + hl;
        bool valid = j < end;
        int sj = valid ? ssrc[j] : 0;
        float asv = as_[sj];
        int rowoff = sj << 6;
        float sc = valid ? lrelu(asv + add) : -1e30f;
        float ex = __expf(sc);
        lacc += ex;

        {   // edges eb+0..15 (groups 0,1)
            int l0 = hbase + e8;
            int l1 = hbase + 8 + e8;
            int ga0 = __shfl(rowoff, l0);
            int ga1 = __shfl(rowoff, l1);
            uint4 q0 = *(const uint4*)(hb + (size_t)((u32)ga0 + boff));
            uint4 q1 = *(const uint4*)(hb + (size_t)((u32)ga1 + boff));
            float w0 = __shfl(ex, l0);
            float w1 = __shfl(ex, l1);
            fma8(w0, q0, acc); fma8(w1, q1, acc);
        }
        if (end - eb > 16) {   // edges eb+16..31 (groups 2,3)
            int l2 = hbase + 16 + e8;
            int l3 = hbase + 24 + e8;
            int ga2 = __shfl(rowoff, l2);
            int ga3 = __shfl(rowoff, l3);
            uint4 q2 = *(const uint4*)(hb + (size_t)((u32)ga2 + boff));
            uint4 q3 = *(const uint4*)(hb + (size_t)((u32)ga3 + boff));
            float w2 = __shfl(ex, l2);
            float w3 = __shfl(ex, l3);
            fma8(w2, q2, acc); fma8(w3, q3, acc);
        }
    }

    #pragma unroll
    for (int off = 16; off > 0; off >>= 1) lacc += __shfl_xor(lacc, off);
    float invl = 1.f / lacc;

    // reduce across 8 edge-slots (stride 4; stays within 32-lane half)
    #pragma unroll
    for (int c = 0; c < 8; ++c) {
        acc[c] += __shfl_xor(acc[c], 4);
        acc[c] += __shfl_xor(acc[c], 8);
        acc[c] += __shfl_xor(acc[c], 16);
    }

    // fused bias + log_softmax: quad lanes (i4) x 8 channels
    float v[8];
    #pragma unroll
    for (int c = 0; c < 8; ++c) v[c] = fmaf(acc[c], invl, ldf(b2, i4 * 8 + c, bf));
    float mx = v[0];
    #pragma unroll
    for (int c = 1; c < 8; ++c) mx = fmaxf(mx, v[c]);
    mx = fmaxf(mx, __shfl_xor(mx, 1));
    mx = fmaxf(mx, __shfl_xor(mx, 2));
    float ss = 0.f;
    #pragma unroll
    for (int c = 0; c < 8; ++c) ss += __expf(v[c] - mx);
    ss += __shfl_xor(ss, 1);
    ss += __shfl_xor(ss, 2);
    float lg = mx + __logf(ss);
    if (e8 == 0 && dreal < N_NODES) {
        *(float4*)&out[(size_t)dst * 32 + i4 * 8] =
            make_float4(v[0] - lg, v[1] - lg, v[2] - lg, v[3] - lg);
        *(float4*)&out[(size_t)dst * 32 + i4 * 8 + 4] =
            make_float4(v[4] - lg, v[5] - lg, v[6] - lg, v[7] - lg);
    }
}

// ---------------------------------------------------------------------------
extern "C" void kernel_launch(void* const* d_in, const int* in_sizes, int n_in,
                              void* d_out, int out_size, void* d_ws, size_t ws_size,
                              hipStream_t stream) {
    const float* x   = (const float*)d_in[0];
    const int* ei    = (const int*)d_in[1];
    const float* W1  = (const float*)d_in[2];
    const void* a_s1 = d_in[3];
    const void* a_d1 = d_in[4];
    const void* b1   = d_in[5];
    const u32* W2    = (const u32*)d_in[6];
    const void* a_s2 = d_in[7];
    const void* a_d2 = d_in[8];
    const void* b2   = d_in[9];
    float* out = (float*)d_out;

    // workspace carve-up (~47 MB)
    char* base = (char*)d_ws;
    int* flags = (int*)base;
    u16* h     = (u16*)(base + 64);                           // N*64 bf16 (layer-1)
    char* q = base + 64 + (size_t)N_NODES * 64 * 2;
    float* as1 = (float*)q; q += (size_t)N_NODES * 4;
    float* ad1 = (float*)q; q += (size_t)N_NODES * 4;
    float* as2 = (float*)q; q += (size_t)N_NODES * 4;
    float* ad2 = (float*)q; q += (size_t)N_NODES * 4;
    u16* h2    = (u16*)q;   q += (size_t)N_NODES * 32 * 2;    // N*32 bf16 (layer-2)
    int* rowptr = (int*)q;  q += (size_t)(N_NODES + 16) * 4;
    int* ssrc   = (int*)q;  q += (size_t)ET * 4;
    int* bcnt   = (int*)q;  q += 256 * 4;
    int* bbase  = (int*)q;  q += 256 * 4;
    q = (char*)(((size_t)q + 255) & ~(size_t)255);            // align 256
    u32*  bbuf  = (u32*)q;                                    // 8.03 MB (sort only)

    detect_kernel<<<1, 64, 0, stream>>>((const u32*)x, ei, flags, bcnt);

    // CSR by dst via 2-pass bucket sort (rowptr built in scatter)
    bin_kernel<<<(ET + BINCH - 1) / BINCH, 256, 0, stream>>>(ei, flags, bcnt, bbuf);
    bscan_kernel<<<1, 256, 0, stream>>>(bcnt, bbase);
    scatter_kernel<<<NBUCK, 1024, 0, stream>>>(bcnt, bbase, bbuf, rowptr, ssrc);

    // layer 1: gemm -> gather (integrated softmax) with fused gemm2
    gemm1_kernel<<<(N_NODES + 255) / 256, 256, 0, stream>>>(x, W1, a_s1, a_d1, flags, h, as1, ad1);
    gather64_g2_kernel<<<(N_NODES + 7) / 8, 256, 0, stream>>>(
        rowptr, ssrc, as1, ad1, h, b1, W2, a_s2, a_d2, flags, h2, as2, ad2);

    // layer 2 (integrated softmax; lsm fused; writes d_out directly)
    gather32_lsm_kernel<<<(N_NODES + 7) / 8, 256, 0, stream>>>(
        rowptr, ssrc, as2, ad2, h2, b2, flags, out);
}